// Round 7
// baseline (123.716 us; speedup 1.0000x reference)
//
#include <hip/hip_runtime.h>
#include <hip/hip_bf16.h>
#include <math.h>

#define HH 128
#define WW 128
#define HW 16384
#define BATCH 8

typedef __attribute__((ext_vector_type(8))) short short8;
typedef __attribute__((ext_vector_type(4))) float f32x4;
typedef __attribute__((ext_vector_type(4))) unsigned int u32x4;

union FragU { short8 v; unsigned int u[4]; u32x4 q; };

static __device__ __forceinline__ unsigned short f2bf(float f) {
    __hip_bfloat16 h = __float2bfloat16(f);
    return *(unsigned short*)&h;
}
static __device__ __forceinline__ float bf_lo(unsigned int r) {
    return __uint_as_float(r << 16);
}
static __device__ __forceinline__ float bf_hi(unsigned int r) {
    return __uint_as_float(r & 0xffff0000u);
}

// ---------------------------------------------------------------------------
// Prep: pack weights into MFMA A-fragment layout, bf16.
// k = s*32 + 8*(l>>4) + j ; c = k&63 ; kk = k>>6  (matches B-side generation)
//   wA : (4,18,64,8) bf16  <- weight (64,64,3,3)
//   owA: (2,18,64,8) bf16  <- offset_w (27,64,3,3), rows>=27 zero
// ---------------------------------------------------------------------------
__global__ __launch_bounds__(256) void prep_kernel(
    const float* __restrict__ weight,
    const float* __restrict__ offset_w,
    unsigned short* __restrict__ wA,
    unsigned short* __restrict__ owA)
{
    int id = blockIdx.x * 256 + threadIdx.x;
    if (id < 4 * 18 * 64) {
        int m = id / (18 * 64);
        int s = (id / 64) % 18;
        int l = id & 63;
        int cout = m * 16 + (l & 15);
        int kbase = s * 32 + 8 * (l >> 4);
#pragma unroll
        for (int j = 0; j < 8; ++j) {
            int k = kbase + j;
            int kk = k >> 6;
            int c = k & 63;
            wA[id * 8 + j] = f2bf(weight[(cout * 64 + c) * 9 + kk]);
        }
        return;
    }
    int id2 = id - 4 * 18 * 64;
    if (id2 < 2 * 18 * 64) {
        int m = id2 / (18 * 64);
        int s = (id2 / 64) % 18;
        int l = id2 & 63;
        int cout = m * 16 + (l & 15);
        int kbase = s * 32 + 8 * (l >> 4);
#pragma unroll
        for (int j = 0; j < 8; ++j) {
            int k = kbase + j;
            int kk = k >> 6;
            int c = k & 63;
            float v = (cout < 27) ? offset_w[(cout * 64 + c) * 9 + kk] : 0.0f;
            owA[id2 * 8 + j] = f2bf(v);
        }
    }
}

// ---------------------------------------------------------------------------
// Transform: x NCHW fp32 -> xT NHWC bf16 (u32 channel-pairs), LDS-tiled.
// ---------------------------------------------------------------------------
__global__ __launch_bounds__(256) void transform_kernel(
    const float* __restrict__ x,
    unsigned int* __restrict__ xT)
{
    __shared__ unsigned int lds[64][33];
    int bid = blockIdx.x;
    int b = bid & 7;                        // image -> XCD
    int pix0 = (bid >> 3) << 6;
    int t = threadIdx.x;
    int px = t & 63;
    int cp0 = (t >> 6) * 8;

    const float* xb = x + (size_t)b * 64 * HW + pix0 + px;
#pragma unroll
    for (int it = 0; it < 8; ++it) {
        int cpair = cp0 + it;
        float2 f2;
        f2.x = xb[(size_t)(2 * cpair) * HW];
        f2.y = xb[(size_t)(2 * cpair + 1) * HW];
        __hip_bfloat162 h2 = __float22bfloat162_rn(f2);
        lds[px][cpair] = *(unsigned int*)&h2;
    }
    __syncthreads();

    int wpx = t >> 2, q = t & 3;
    unsigned int* dst = xT + ((size_t)b * HW + pix0 + wpx) * 32 + q * 8;
    u32x4 a, c;
#pragma unroll
    for (int j = 0; j < 4; ++j) a[j] = lds[wpx][q * 8 + j];
#pragma unroll
    for (int j = 0; j < 4; ++j) c[j] = lds[wpx][q * 8 + 4 + j];
    *(u32x4*)dst = a;
    *(u32x4*)(dst + 4) = c;
}

// ---------------------------------------------------------------------------
// Fused kernel, barrier-free + software-pipelined.
//   phase 1: offset conv (MFMA, M=27). Static taps prefetched depth-1;
//            A-frags loaded directly (coalesced 1KB, L2-resident).
//            Results -> per-WAVE LDS slice red[wid] (no cross-wave deps,
//            so NO __syncthreads anywhere in this kernel).
//   phase 2: deformable conv (MFMA, M=64). All offsets known after phase 1;
//            the 8 corner gathers of kk+1 are issued a full iteration early
//            (~600cy cover); A-frag loads issued before the bilerp (~270cy
//            VALU cover). red padded [27][17] -> conflict-free.
// Block = 4 waves x 16 px; lane: pixel q=l&15, channel-group g=l>>4.
// ---------------------------------------------------------------------------
__global__ __launch_bounds__(256, 3) void fused_kernel(
    const unsigned int* __restrict__ xT,    // NHWC bf16
    const unsigned short* __restrict__ wA,  // (4,18,64,8) bf16
    const unsigned short* __restrict__ owA, // (2,18,64,8) bf16
    const float* __restrict__ bias,         // (64,)
    const float* __restrict__ offset_b,     // (27,)
    float* __restrict__ out)                // (B,64,HW) f32
{
    __shared__ float red[4][27][17];        // per-wave off/mask, padded

    int t = threadIdx.x;
    int lane = t & 63;
    int wid = t >> 6;
    int bid = blockIdx.x;
    int b = bid & 7;                        // image -> XCD
    int p = ((bid >> 3) * 4 + wid) * 16 + (lane & 15);
    int ho = p >> 7, wo = p & 127;
    int g = lane >> 4;
    int q = lane & 15;

    const u32x4* xbv = (const u32x4*)(xT + (size_t)b * HW * 32);
    const short8* wAv = (const short8*)wA;
    const short8* owAv = (const short8*)owA;

    // ================= phase 1: offset conv =================
    f32x4 acc1[2];
#pragma unroll
    for (int m = 0; m < 2; ++m) {
#pragma unroll
        for (int r = 0; r < 4; ++r) {
            int cout = m * 16 + g * 4 + r;
            acc1[m][r] = (cout < 27) ? offset_b[cout] : 0.0f;
        }
    }

#define TAPK(KK, OK, T0, T1) {                                              \
        int iy = ho + (KK) / 3 - 1;                                         \
        int ix = wo + (KK) % 3 - 1;                                         \
        OK = ((unsigned)iy < 128u) && ((unsigned)ix < 128u);                \
        int iyc = min(max(iy, 0), 127);                                     \
        int ixc = min(max(ix, 0), 127);                                     \
        const u32x4* pp = xbv + (size_t)(iyc * WW + ixc) * 8 + g;           \
        T0 = pp[0]; T1 = pp[4];                                             \
    }

    bool okc; u32x4 t0, t1;
    TAPK(0, okc, t0, t1);
#pragma unroll
    for (int kk = 0; kk < 9; ++kk) {
        bool okn = false; u32x4 nt0 = {}, nt1 = {};
        if (kk < 8) TAPK(kk + 1, okn, nt0, nt1);

        short8 a00 = owAv[(2 * kk) * 64 + lane];
        short8 a01 = owAv[(2 * kk + 1) * 64 + lane];
        short8 a10 = owAv[(18 + 2 * kk) * 64 + lane];
        short8 a11 = owAv[(18 + 2 * kk + 1) * 64 + lane];

        FragU bf0, bf1;
#pragma unroll
        for (int j = 0; j < 4; ++j) {
            bf0.u[j] = okc ? t0[j] : 0u;
            bf1.u[j] = okc ? t1[j] : 0u;
        }
        acc1[0] = __builtin_amdgcn_mfma_f32_16x16x32_bf16(a00, bf0.v, acc1[0], 0, 0, 0);
        acc1[0] = __builtin_amdgcn_mfma_f32_16x16x32_bf16(a01, bf1.v, acc1[0], 0, 0, 0);
        acc1[1] = __builtin_amdgcn_mfma_f32_16x16x32_bf16(a10, bf0.v, acc1[1], 0, 0, 0);
        acc1[1] = __builtin_amdgcn_mfma_f32_16x16x32_bf16(a11, bf1.v, acc1[1], 0, 0, 0);
        t0 = nt0; t1 = nt1; okc = okn;
    }

    // redistribute within the wave (per-wid slice -> no barrier needed)
#pragma unroll
    for (int m = 0; m < 2; ++m) {
#pragma unroll
        for (int r = 0; r < 4; ++r) {
            int cout = m * 16 + g * 4 + r;
            if (cout < 27) {
                float a = acc1[m][r];
                if (cout >= 18) a = 1.0f / (1.0f + __expf(-a));
                red[wid][cout][q] = a;
            }
        }
    }

    // ================= phase 2: deformable conv =================
    f32x4 acc[4];
#pragma unroll
    for (int m = 0; m < 4; ++m) {
        acc[m] = *(const f32x4*)(bias + m * 16 + g * 4);
    }

    // corner loads for step KK: weights W0..W3, data D0..D7
    // D0=p00.h0 D1=p00.h1 D2=p01.h0 D3=p01.h1 D4=p10.h0 D5=p10.h1 D6=p11.h0 D7=p11.h1
#define LOADK(KK, W0, W1, W2, W3, D0, D1, D2, D3, D4, D5, D6, D7) {         \
        float dy = red[wid][2 * (KK)][q];                                   \
        float dx = red[wid][2 * (KK) + 1][q];                               \
        float mm = red[wid][18 + (KK)][q];                                  \
        float py = dy + (float)((KK) / 3 + ho - 1);                         \
        float px = dx + (float)((KK) % 3 + wo - 1);                         \
        float y0f = floorf(py), x0f = floorf(px);                           \
        float wy = py - y0f, wx = px - x0f;                                 \
        int y0 = (int)y0f, x0 = (int)x0f;                                   \
        int y1 = y0 + 1, x1 = x0 + 1;                                       \
        bool y0ok = (unsigned)y0 < 128u, y1ok = (unsigned)y1 < 128u;        \
        bool x0ok = (unsigned)x0 < 128u, x1ok = (unsigned)x1 < 128u;        \
        W0 = (y0ok && x0ok) ? (1.0f - wy) * (1.0f - wx) * mm : 0.0f;        \
        W1 = (y0ok && x1ok) ? (1.0f - wy) * wx * mm : 0.0f;                 \
        W2 = (y1ok && x0ok) ? wy * (1.0f - wx) * mm : 0.0f;                 \
        W3 = (y1ok && x1ok) ? wy * wx * mm : 0.0f;                          \
        int y0c = min(max(y0, 0), 127), y1c = min(max(y1, 0), 127);         \
        int x0c = min(max(x0, 0), 127), x1c = min(max(x1, 0), 127);         \
        const u32x4* p00 = xbv + (size_t)(y0c * WW + x0c) * 8 + g;          \
        const u32x4* p01 = xbv + (size_t)(y0c * WW + x1c) * 8 + g;          \
        const u32x4* p10 = xbv + (size_t)(y1c * WW + x0c) * 8 + g;          \
        const u32x4* p11 = xbv + (size_t)(y1c * WW + x1c) * 8 + g;          \
        D0 = p00[0]; D1 = p00[4];                                           \
        D2 = p01[0]; D3 = p01[4];                                           \
        D4 = p10[0]; D5 = p10[4];                                           \
        D6 = p11[0]; D7 = p11[4];                                           \
    }

    float wc0, wc1, wc2, wc3;
    u32x4 c0, c1, c2, c3, c4, c5, c6, c7;
    LOADK(0, wc0, wc1, wc2, wc3, c0, c1, c2, c3, c4, c5, c6, c7);

#pragma unroll
    for (int kk = 0; kk < 9; ++kk) {
        float wn0 = 0, wn1 = 0, wn2 = 0, wn3 = 0;
        u32x4 n0 = {}, n1 = {}, n2 = {}, n3 = {}, n4 = {}, n5 = {}, n6 = {}, n7 = {};
        if (kk < 8) LOADK(kk + 1, wn0, wn1, wn2, wn3, n0, n1, n2, n3, n4, n5, n6, n7);

        // A-fragment loads for this kk (coalesced 1KB each, L2-resident),
        // issued before the bilerp so ~270cy of VALU covers their latency.
        short8 a00 = wAv[(0 * 18 + 2 * kk) * 64 + lane];
        short8 a01 = wAv[(0 * 18 + 2 * kk + 1) * 64 + lane];
        short8 a10 = wAv[(1 * 18 + 2 * kk) * 64 + lane];
        short8 a11 = wAv[(1 * 18 + 2 * kk + 1) * 64 + lane];
        short8 a20 = wAv[(2 * 18 + 2 * kk) * 64 + lane];
        short8 a21 = wAv[(2 * 18 + 2 * kk + 1) * 64 + lane];
        short8 a30 = wAv[(3 * 18 + 2 * kk) * 64 + lane];
        short8 a31 = wAv[(3 * 18 + 2 * kk + 1) * 64 + lane];

        FragU bf0, bf1;
#pragma unroll
        for (int d = 0; d < 4; ++d) {
            float se = fmaf(bf_lo(c6[d]), wc3, fmaf(bf_lo(c4[d]), wc2,
                       fmaf(bf_lo(c2[d]), wc1, bf_lo(c0[d]) * wc0)));
            float so = fmaf(bf_hi(c6[d]), wc3, fmaf(bf_hi(c4[d]), wc2,
                       fmaf(bf_hi(c2[d]), wc1, bf_hi(c0[d]) * wc0)));
            float2 f2; f2.x = se; f2.y = so;
            __hip_bfloat162 h2 = __float22bfloat162_rn(f2);
            bf0.u[d] = *(unsigned int*)&h2;
        }
#pragma unroll
        for (int d = 0; d < 4; ++d) {
            float se = fmaf(bf_lo(c7[d]), wc3, fmaf(bf_lo(c5[d]), wc2,
                       fmaf(bf_lo(c3[d]), wc1, bf_lo(c1[d]) * wc0)));
            float so = fmaf(bf_hi(c7[d]), wc3, fmaf(bf_hi(c5[d]), wc2,
                       fmaf(bf_hi(c3[d]), wc1, bf_hi(c1[d]) * wc0)));
            float2 f2; f2.x = se; f2.y = so;
            __hip_bfloat162 h2 = __float22bfloat162_rn(f2);
            bf1.u[d] = *(unsigned int*)&h2;
        }

        acc[0] = __builtin_amdgcn_mfma_f32_16x16x32_bf16(a00, bf0.v, acc[0], 0, 0, 0);
        acc[0] = __builtin_amdgcn_mfma_f32_16x16x32_bf16(a01, bf1.v, acc[0], 0, 0, 0);
        acc[1] = __builtin_amdgcn_mfma_f32_16x16x32_bf16(a10, bf0.v, acc[1], 0, 0, 0);
        acc[1] = __builtin_amdgcn_mfma_f32_16x16x32_bf16(a11, bf1.v, acc[1], 0, 0, 0);
        acc[2] = __builtin_amdgcn_mfma_f32_16x16x32_bf16(a20, bf0.v, acc[2], 0, 0, 0);
        acc[2] = __builtin_amdgcn_mfma_f32_16x16x32_bf16(a21, bf1.v, acc[2], 0, 0, 0);
        acc[3] = __builtin_amdgcn_mfma_f32_16x16x32_bf16(a30, bf0.v, acc[3], 0, 0, 0);
        acc[3] = __builtin_amdgcn_mfma_f32_16x16x32_bf16(a31, bf1.v, acc[3], 0, 0, 0);

        c0 = n0; c1 = n1; c2 = n2; c3 = n3;
        c4 = n4; c5 = n5; c6 = n6; c7 = n7;
        wc0 = wn0; wc1 = wn1; wc2 = wn2; wc3 = wn3;
    }

    // D: row(cout) = m*16 + g*4 + r, col(pixel) = lane&15
#pragma unroll
    for (int m = 0; m < 4; ++m) {
#pragma unroll
        for (int r = 0; r < 4; ++r) {
            int cout = m * 16 + g * 4 + r;
            out[((size_t)b * 64 + cout) * HW + p] = acc[m][r];
        }
    }
}

// ---------------------------------------------------------------------------
extern "C" void kernel_launch(void* const* d_in, const int* in_sizes, int n_in,
                              void* d_out, int out_size, void* d_ws, size_t ws_size,
                              hipStream_t stream) {
    const float* x        = (const float*)d_in[0];
    const float* weight   = (const float*)d_in[1];
    const float* bias     = (const float*)d_in[2];
    const float* offset_w = (const float*)d_in[3];
    const float* offset_b = (const float*)d_in[4];
    float* out = (float*)d_out;

    unsigned int* xT = (unsigned int*)d_ws;                                // B*HW*32 u32 = 16MB
    unsigned short* wA  = (unsigned short*)(xT + (size_t)BATCH * HW * 32); // 4*18*64*8
    unsigned short* owA = wA + 4 * 18 * 64 * 8;                            // 2*18*64*8

    prep_kernel<<<27, 256, 0, stream>>>(weight, offset_w, wA, owA);

    int n_tiles = BATCH * HW / 64;   // 2048
    transform_kernel<<<n_tiles, 256, 0, stream>>>(x, xT);

    int n_blocks = BATCH * HW / 64;  // 2048 (4 waves x 16 px)
    fused_kernel<<<n_blocks, 256, 0, stream>>>(xT, wA, owA, bias, offset_b, out);
}

// Round 8
// 112.767 us; speedup vs baseline: 1.0971x; 1.0971x over previous
//
#include <hip/hip_runtime.h>
#include <hip/hip_bf16.h>
#include <math.h>

#define HH 128
#define WW 128
#define HW 16384
#define BATCH 8

typedef __attribute__((ext_vector_type(8))) short short8;
typedef __attribute__((ext_vector_type(16))) float f32x16;
typedef __attribute__((ext_vector_type(4))) unsigned int u32x4;

union FragU { short8 v; unsigned int u[4]; u32x4 q; };

static __device__ __forceinline__ unsigned short f2bf(float f) {
    __hip_bfloat16 h = __float2bfloat16(f);
    return *(unsigned short*)&h;
}
static __device__ __forceinline__ float bf_lo(unsigned int r) {
    return __uint_as_float(r << 16);
}
static __device__ __forceinline__ float bf_hi(unsigned int r) {
    return __uint_as_float(r & 0xffff0000u);
}
static __device__ __forceinline__ short8 bilerp_frag(
    u32x4 r00, u32x4 r01, u32x4 r10, u32x4 r11,
    float w0, float w1, float w2, float w3)
{
    FragU bf;
#pragma unroll
    for (int d = 0; d < 4; ++d) {
        float se = fmaf(bf_lo(r11[d]), w3, fmaf(bf_lo(r10[d]), w2,
                   fmaf(bf_lo(r01[d]), w1, bf_lo(r00[d]) * w0)));
        float so = fmaf(bf_hi(r11[d]), w3, fmaf(bf_hi(r10[d]), w2,
                   fmaf(bf_hi(r01[d]), w1, bf_hi(r00[d]) * w0)));
        float2 f2; f2.x = se; f2.y = so;
        __hip_bfloat162 h2 = __float22bfloat162_rn(f2);
        bf.u[d] = *(unsigned int*)&h2;
    }
    return bf.v;
}

// ---------------------------------------------------------------------------
// Prep: pack weights for 32x32x16 MFMA A-operand, bf16.
// A lane l: row = l&31, k-elems j=0..7 -> channel c = s*16 + 8*(l>>5) + j
// (k-slot map identical on B side -> any HW slot permutation cancels).
//   wA : (m=2, kk=9, s=4, lane=64, j=8) bf16   <- weight (64,64,3,3)
//   owA: (kk=9, s=4, lane=64, j=8)      bf16   <- offset_w (27,64,3,3), rows>=27 zero
// ---------------------------------------------------------------------------
__global__ __launch_bounds__(256) void prep_kernel(
    const float* __restrict__ weight,
    const float* __restrict__ offset_w,
    unsigned short* __restrict__ wA,
    unsigned short* __restrict__ owA)
{
    int id = blockIdx.x * 256 + threadIdx.x;
    if (id < 4608) {                        // 2*9*4*64
        int m = id / 2304;
        int rem = id % 2304;
        int kk = rem >> 8;                  // /256
        int s = (rem >> 6) & 3;
        int l = id & 63;
        int cout = m * 32 + (l & 31);
        int cbase = s * 16 + 8 * (l >> 5);
#pragma unroll
        for (int j = 0; j < 8; ++j) {
            wA[id * 8 + j] = f2bf(weight[(cout * 64 + cbase + j) * 9 + kk]);
        }
        return;
    }
    int id2 = id - 4608;
    if (id2 < 2304) {                       // 9*4*64
        int kk = id2 >> 8;
        int s = (id2 >> 6) & 3;
        int l = id2 & 63;
        int cout = l & 31;
        int cbase = s * 16 + 8 * (l >> 5);
#pragma unroll
        for (int j = 0; j < 8; ++j) {
            float v = (cout < 27) ? offset_w[(cout * 64 + cbase + j) * 9 + kk] : 0.0f;
            owA[id2 * 8 + j] = f2bf(v);
        }
    }
}

// ---------------------------------------------------------------------------
// Transform: x NCHW fp32 -> xT NHWC bf16 (u32 channel-pairs), LDS-tiled.
// ---------------------------------------------------------------------------
__global__ __launch_bounds__(256) void transform_kernel(
    const float* __restrict__ x,
    unsigned int* __restrict__ xT)
{
    __shared__ unsigned int lds[64][33];
    int bid = blockIdx.x;
    int b = bid & 7;                        // image -> XCD
    int pix0 = (bid >> 3) << 6;
    int t = threadIdx.x;
    int px = t & 63;
    int cp0 = (t >> 6) * 8;

    const float* xb = x + (size_t)b * 64 * HW + pix0 + px;
#pragma unroll
    for (int it = 0; it < 8; ++it) {
        int cpair = cp0 + it;
        float2 f2;
        f2.x = xb[(size_t)(2 * cpair) * HW];
        f2.y = xb[(size_t)(2 * cpair + 1) * HW];
        __hip_bfloat162 h2 = __float22bfloat162_rn(f2);
        lds[px][cpair] = *(unsigned int*)&h2;
    }
    __syncthreads();

    int wpx = t >> 2, q = t & 3;
    unsigned int* dst = xT + ((size_t)b * HW + pix0 + wpx) * 32 + q * 8;
    u32x4 a, c;
#pragma unroll
    for (int j = 0; j < 4; ++j) a[j] = lds[wpx][q * 8 + j];
#pragma unroll
    for (int j = 0; j < 4; ++j) c[j] = lds[wpx][q * 8 + 4 + j];
    *(u32x4*)dst = a;
    *(u32x4*)(dst + 4) = c;
}

// ---------------------------------------------------------------------------
// Fused kernel on 32x32x16 MFMA: wave = 32 pixels, barrier-free.
//   phase 1: offset conv (M=32, 27 used). Taps depth-1 prefetched.
//   phase 2: deform conv (M=64 = 2 m-tiles). 2-buffer k-step rotation:
//            while k-step s computes (bilerp 64 VALU + 2 MFMA), step s+1's
//            4 corner u32x4 + 2 A-frags are in flight. ~24 transient regs
//            per buffer (r7's 16-deep pipeline spilled; this stays small).
//   A-frag TA traffic 4x lower than 16x16 version (8B/lane, 32px amortize).
// Block = 4 waves x 32 px; lane: pixel q=l&31, k-half hi=l>>5.
// ---------------------------------------------------------------------------
__global__ __launch_bounds__(256, 4) void fused_kernel(
    const unsigned int* __restrict__ xT,    // NHWC bf16
    const unsigned short* __restrict__ wA,  // (2,9,4,64,8) bf16
    const unsigned short* __restrict__ owA, // (9,4,64,8) bf16
    const float* __restrict__ bias,         // (64,)
    const float* __restrict__ offset_b,     // (27,)
    float* __restrict__ out)                // (B,64,HW) f32
{
    __shared__ float red[4][27][33];        // per-wave off/mask, padded

    int t = threadIdx.x;
    int lane = t & 63;
    int wid = t >> 6;
    int bid = blockIdx.x;
    int b = bid & 7;                        // image -> XCD
    int q = lane & 31;                      // pixel within wave
    int hi = lane >> 5;                     // k-half
    int p = ((bid >> 3) * 4 + wid) * 32 + q;
    int ho = p >> 7, wo = p & 127;
    int cg = 4 * hi;                        // u32 offset of this lane's channels

    const unsigned int* xb = xT + (size_t)b * HW * 32;
    const short8* wAv = (const short8*)wA;
    const short8* owAv = (const short8*)owA;

    // ================= phase 1: offset conv =================
    f32x16 acc1 = {};

#define P1ADDR(KK, OK, BASE) {                                              \
        int iy = ho + (KK) / 3 - 1;                                         \
        int ix = wo + (KK) % 3 - 1;                                         \
        OK = ((unsigned)iy < 128u) && ((unsigned)ix < 128u);                \
        BASE = (min(max(iy, 0), 127) * WW + min(max(ix, 0), 127)) * 32 + cg;\
    }

    bool okc; int tbc;
    P1ADDR(0, okc, tbc);
    u32x4 tc[4];
    tc[0] = *(const u32x4*)(xb + tbc);
    tc[1] = *(const u32x4*)(xb + tbc + 8);
    tc[2] = *(const u32x4*)(xb + tbc + 16);
    tc[3] = *(const u32x4*)(xb + tbc + 24);

    for (int kk = 0; kk < 9; ++kk) {
        bool okn = false; int tbn = 0;
        u32x4 tn[4] = {};
        if (kk < 8) {
            P1ADDR(kk + 1, okn, tbn);
            tn[0] = *(const u32x4*)(xb + tbn);
            tn[1] = *(const u32x4*)(xb + tbn + 8);
            tn[2] = *(const u32x4*)(xb + tbn + 16);
            tn[3] = *(const u32x4*)(xb + tbn + 24);
        }
#pragma unroll
        for (int s = 0; s < 4; ++s) {
            short8 a = owAv[(kk * 4 + s) * 64 + lane];
            FragU bf;
#pragma unroll
            for (int j = 0; j < 4; ++j) bf.u[j] = okc ? tc[s][j] : 0u;
            acc1 = __builtin_amdgcn_mfma_f32_32x32x16_bf16(a, bf.v, acc1, 0, 0, 0);
        }
#pragma unroll
        for (int s = 0; s < 4; ++s) tc[s] = tn[s];
        okc = okn;
    }

    // redistribute within wave: D row=(r&3)+8*(r>>2)+4*hi, col=q
#pragma unroll
    for (int r = 0; r < 16; ++r) {
        int cout = (r & 3) + 8 * (r >> 2) + 4 * hi;
        if (cout < 27) {
            float a = acc1[r] + offset_b[cout];
            if (cout >= 18) a = 1.0f / (1.0f + __expf(-a));
            red[wid][cout][q] = a;
        }
    }

    // ================= phase 2: deformable conv =================
    f32x16 acc[2];
#pragma unroll
    for (int m = 0; m < 2; ++m) {
#pragma unroll
        for (int r = 0; r < 16; ++r) {
            acc[m][r] = bias[m * 32 + (r & 3) + 8 * (r >> 2) + 4 * hi];
        }
    }

#define P2ADDR(KK, W0, W1, W2, W3, O00, O01, O10, O11) {                    \
        float dy = red[wid][2 * (KK)][q];                                   \
        float dx = red[wid][2 * (KK) + 1][q];                               \
        float mm = red[wid][18 + (KK)][q];                                  \
        float py = dy + (float)((KK) / 3 + ho - 1);                         \
        float px = dx + (float)((KK) % 3 + wo - 1);                         \
        float y0f = floorf(py), x0f = floorf(px);                           \
        float wy = py - y0f, wx = px - x0f;                                 \
        int y0 = (int)y0f, x0 = (int)x0f;                                   \
        int y1 = y0 + 1, x1 = x0 + 1;                                       \
        bool y0ok = (unsigned)y0 < 128u, y1ok = (unsigned)y1 < 128u;        \
        bool x0ok = (unsigned)x0 < 128u, x1ok = (unsigned)x1 < 128u;        \
        W0 = (y0ok && x0ok) ? (1.0f - wy) * (1.0f - wx) * mm : 0.0f;        \
        W1 = (y0ok && x1ok) ? (1.0f - wy) * wx * mm : 0.0f;                 \
        W2 = (y1ok && x0ok) ? wy * (1.0f - wx) * mm : 0.0f;                 \
        W3 = (y1ok && x1ok) ? wy * wx * mm : 0.0f;                          \
        int y0c = min(max(y0, 0), 127), y1c = min(max(y1, 0), 127);         \
        int x0c = min(max(x0, 0), 127), x1c = min(max(x1, 0), 127);         \
        O00 = (y0c * WW + x0c) * 32 + cg;                                   \
        O01 = (y0c * WW + x1c) * 32 + cg;                                   \
        O10 = (y1c * WW + x0c) * 32 + cg;                                   \
        O11 = (y1c * WW + x1c) * 32 + cg;                                   \
    }
#define LDX(O) (*(const u32x4*)(xb + (O)))
#define MFMA32(A, B, C) __builtin_amdgcn_mfma_f32_32x32x16_bf16(A, B, C, 0, 0, 0)

    float cw0, cw1, cw2, cw3;
    int co00, co01, co10, co11;
    P2ADDR(0, cw0, cw1, cw2, cw3, co00, co01, co10, co11);
    u32x4 ba0 = LDX(co00), ba1 = LDX(co01), ba2 = LDX(co10), ba3 = LDX(co11);
    short8 aa0 = wAv[lane];                 // m=0, kk=0, s=0
    short8 aa1 = wAv[36 * 64 + lane];       // m=1

    for (int kk = 0; kk < 9; ++kk) {
        int base = kk * 4;
        int kn = (kk < 8) ? kk + 1 : 8;

        // --- step 0: prefetch s=1 -> B; consume A(s=0)
        u32x4 bb0 = LDX(co00 + 8), bb1 = LDX(co01 + 8), bb2 = LDX(co10 + 8), bb3 = LDX(co11 + 8);
        short8 ab0 = wAv[(base + 1) * 64 + lane];
        short8 ab1 = wAv[(36 + base + 1) * 64 + lane];
        {
            short8 bf = bilerp_frag(ba0, ba1, ba2, ba3, cw0, cw1, cw2, cw3);
            acc[0] = MFMA32(aa0, bf, acc[0]);
            acc[1] = MFMA32(aa1, bf, acc[1]);
        }
        // --- step 1: prefetch s=2 -> A; consume B(s=1)
        ba0 = LDX(co00 + 16); ba1 = LDX(co01 + 16); ba2 = LDX(co10 + 16); ba3 = LDX(co11 + 16);
        aa0 = wAv[(base + 2) * 64 + lane];
        aa1 = wAv[(36 + base + 2) * 64 + lane];
        {
            short8 bf = bilerp_frag(bb0, bb1, bb2, bb3, cw0, cw1, cw2, cw3);
            acc[0] = MFMA32(ab0, bf, acc[0]);
            acc[1] = MFMA32(ab1, bf, acc[1]);
        }
        // --- step 2: compute next-kk addresses; prefetch s=3 -> B; consume A(s=2)
        float nw0, nw1, nw2, nw3;
        int no00, no01, no10, no11;
        P2ADDR(kn, nw0, nw1, nw2, nw3, no00, no01, no10, no11);
        bb0 = LDX(co00 + 24); bb1 = LDX(co01 + 24); bb2 = LDX(co10 + 24); bb3 = LDX(co11 + 24);
        ab0 = wAv[(base + 3) * 64 + lane];
        ab1 = wAv[(36 + base + 3) * 64 + lane];
        {
            short8 bf = bilerp_frag(ba0, ba1, ba2, ba3, cw0, cw1, cw2, cw3);
            acc[0] = MFMA32(aa0, bf, acc[0]);
            acc[1] = MFMA32(aa1, bf, acc[1]);
        }
        // --- step 3: prefetch next kk s=0 -> A; consume B(s=3)
        int nbase = kn * 4;
        ba0 = LDX(no00); ba1 = LDX(no01); ba2 = LDX(no10); ba3 = LDX(no11);
        aa0 = wAv[nbase * 64 + lane];
        aa1 = wAv[(36 + nbase) * 64 + lane];
        {
            short8 bf = bilerp_frag(bb0, bb1, bb2, bb3, cw0, cw1, cw2, cw3);
            acc[0] = MFMA32(ab0, bf, acc[0]);
            acc[1] = MFMA32(ab1, bf, acc[1]);
        }
        cw0 = nw0; cw1 = nw1; cw2 = nw2; cw3 = nw3;
        co00 = no00; co01 = no01; co10 = no10; co11 = no11;
    }

    // D: row(cout) = m*32 + (r&3)+8*(r>>2)+4*hi, col(pixel) = q
#pragma unroll
    for (int m = 0; m < 2; ++m) {
#pragma unroll
        for (int r = 0; r < 16; ++r) {
            int cout = m * 32 + (r & 3) + 8 * (r >> 2) + 4 * hi;
            out[((size_t)b * 64 + cout) * HW + p] = acc[m][r];
        }
    }
}

// ---------------------------------------------------------------------------
extern "C" void kernel_launch(void* const* d_in, const int* in_sizes, int n_in,
                              void* d_out, int out_size, void* d_ws, size_t ws_size,
                              hipStream_t stream) {
    const float* x        = (const float*)d_in[0];
    const float* weight   = (const float*)d_in[1];
    const float* bias     = (const float*)d_in[2];
    const float* offset_w = (const float*)d_in[3];
    const float* offset_b = (const float*)d_in[4];
    float* out = (float*)d_out;

    unsigned int* xT = (unsigned int*)d_ws;                                // B*HW*32 u32 = 16MB
    unsigned short* wA  = (unsigned short*)(xT + (size_t)BATCH * HW * 32); // 4608*8 = 72KB
    unsigned short* owA = wA + 4608 * 8;                                   // 2304*8 = 36KB

    prep_kernel<<<27, 256, 0, stream>>>(weight, offset_w, wA, owA);

    int n_tiles = BATCH * HW / 64;   // 2048
    transform_kernel<<<n_tiles, 256, 0, stream>>>(x, xT);

    int n_blocks = BATCH * HW / 128; // 1024 (4 waves x 32 px)
    fused_kernel<<<n_blocks, 256, 0, stream>>>(xT, wA, owA, bias, offset_b, out);
}

// Round 9
// 110.572 us; speedup vs baseline: 1.1189x; 1.0198x over previous
//
#include <hip/hip_runtime.h>
#include <hip/hip_bf16.h>
#include <math.h>

#define HH 128
#define WW 128
#define HW 16384
#define BATCH 8

// 2D tile geometry (fused kernel)
#define TR 8            // tile rows per block
#define TC 16           // tile cols per block
#define HALO 2
#define PR 12           // TR + 2*HALO
#define PC 20           // TC + 2*HALO
#define PST 36          // dwords per patch pixel (32 data + 4 pad: keeps 16B align, rotates banks)

typedef __attribute__((ext_vector_type(8))) short short8;
typedef __attribute__((ext_vector_type(16))) float f32x16;
typedef __attribute__((ext_vector_type(4))) unsigned int u32x4;

union FragU { short8 v; unsigned int u[4]; u32x4 q; };

static __device__ __forceinline__ unsigned short f2bf(float f) {
    __hip_bfloat16 h = __float2bfloat16(f);
    return *(unsigned short*)&h;
}
static __device__ __forceinline__ float bf_lo(unsigned int r) {
    return __uint_as_float(r << 16);
}
static __device__ __forceinline__ float bf_hi(unsigned int r) {
    return __uint_as_float(r & 0xffff0000u);
}
static __device__ __forceinline__ short8 bilerp_frag(
    u32x4 r00, u32x4 r01, u32x4 r10, u32x4 r11,
    float w0, float w1, float w2, float w3)
{
    FragU bf;
#pragma unroll
    for (int d = 0; d < 4; ++d) {
        float se = fmaf(bf_lo(r11[d]), w3, fmaf(bf_lo(r10[d]), w2,
                   fmaf(bf_lo(r01[d]), w1, bf_lo(r00[d]) * w0)));
        float so = fmaf(bf_hi(r11[d]), w3, fmaf(bf_hi(r10[d]), w2,
                   fmaf(bf_hi(r01[d]), w1, bf_hi(r00[d]) * w0)));
        float2 f2; f2.x = se; f2.y = so;
        __hip_bfloat162 h2 = __float22bfloat162_rn(f2);
        bf.u[d] = *(unsigned int*)&h2;
    }
    return bf.v;
}

// register index inside f32x16 acc that holds D-row `row` (32x32 layout):
// row = (r&3) + 8*(r>>2) + 4*hi  =>  r = (row&3) | ((row>>3)<<2), hi = (row>>2)&1
#define RR(row) (((row) & 3) | (((row) >> 3) << 2))
#define HB(row) ((((row) >> 2) & 1) << 5)

// ---------------------------------------------------------------------------
// Prep: pack weights for 32x32x16 MFMA A-operand, bf16 (verified in r8).
// A lane l: row = l&31, k-elems j=0..7 -> channel c = s*16 + 8*(l>>5) + j
//   wA : (m=2, kk=9, s=4, lane=64, j=8) bf16   <- weight (64,64,3,3)
//   owA: (kk=9, s=4, lane=64, j=8)      bf16   <- offset_w (27,64,3,3), rows>=27 zero
// ---------------------------------------------------------------------------
__global__ __launch_bounds__(256) void prep_kernel(
    const float* __restrict__ weight,
    const float* __restrict__ offset_w,
    unsigned short* __restrict__ wA,
    unsigned short* __restrict__ owA)
{
    int id = blockIdx.x * 256 + threadIdx.x;
    if (id < 4608) {                        // 2*9*4*64
        int m = id / 2304;
        int rem = id % 2304;
        int kk = rem >> 8;
        int s = (rem >> 6) & 3;
        int l = id & 63;
        int cout = m * 32 + (l & 31);
        int cbase = s * 16 + 8 * (l >> 5);
#pragma unroll
        for (int j = 0; j < 8; ++j) {
            wA[id * 8 + j] = f2bf(weight[(cout * 64 + cbase + j) * 9 + kk]);
        }
        return;
    }
    int id2 = id - 4608;
    if (id2 < 2304) {                       // 9*4*64
        int kk = id2 >> 8;
        int s = (id2 >> 6) & 3;
        int l = id2 & 63;
        int cout = l & 31;
        int cbase = s * 16 + 8 * (l >> 5);
#pragma unroll
        for (int j = 0; j < 8; ++j) {
            float v = (cout < 27) ? offset_w[(cout * 64 + cbase + j) * 9 + kk] : 0.0f;
            owA[id2 * 8 + j] = f2bf(v);
        }
    }
}

// ---------------------------------------------------------------------------
// Transform: x NCHW fp32 -> xT NHWC bf16 (u32 channel-pairs), LDS-tiled.
// ---------------------------------------------------------------------------
__global__ __launch_bounds__(256) void transform_kernel(
    const float* __restrict__ x,
    unsigned int* __restrict__ xT)
{
    __shared__ unsigned int lds[64][33];
    int bid = blockIdx.x;
    int b = bid & 7;                        // image -> XCD
    int pix0 = (bid >> 3) << 6;
    int t = threadIdx.x;
    int px = t & 63;
    int cp0 = (t >> 6) * 8;

    const float* xb = x + (size_t)b * 64 * HW + pix0 + px;
#pragma unroll
    for (int it = 0; it < 8; ++it) {
        int cpair = cp0 + it;
        float2 f2;
        f2.x = xb[(size_t)(2 * cpair) * HW];
        f2.y = xb[(size_t)(2 * cpair + 1) * HW];
        __hip_bfloat162 h2 = __float22bfloat162_rn(f2);
        lds[px][cpair] = *(unsigned int*)&h2;
    }
    __syncthreads();

    int wpx = t >> 2, qq = t & 3;
    unsigned int* dst = xT + ((size_t)b * HW + pix0 + wpx) * 32 + qq * 8;
    u32x4 a, c;
#pragma unroll
    for (int j = 0; j < 4; ++j) a[j] = lds[wpx][qq * 8 + j];
#pragma unroll
    for (int j = 0; j < 4; ++j) c[j] = lds[wpx][qq * 8 + 4 + j];
    *(u32x4*)dst = a;
    *(u32x4*)(dst + 4) = c;
}

// ---------------------------------------------------------------------------
// Fused kernel, LDS-patch edition.
//   Block = 8x16 pixel tile (4 waves x 32 px as 2x16 sub-tiles).
//   Stage: (12x20) px patch of NHWC bf16 -> LDS (coalesced; ONE barrier).
//   Phase 1 (offset conv) + phase 2 (deform) read all taps/corners via
//   ds_read_b128 -- removes the scattered-gather TA serialization (~55
//   cyc/instr) that bounded r5-r8. Offsets pass phase1->phase2 via __shfl
//   (no LDS red array). Rare out-of-patch samples (|offset|>~2) take an
//   exact global-gather fallback per kk, gated by __all().
// ---------------------------------------------------------------------------
__global__ __launch_bounds__(256, 4) void fused_kernel(
    const unsigned int* __restrict__ xT,    // NHWC bf16
    const unsigned short* __restrict__ wA,  // (2,9,4,64,8) bf16
    const unsigned short* __restrict__ owA, // (9,4,64,8) bf16
    const float* __restrict__ bias,         // (64,)
    const float* __restrict__ offset_b,     // (27,)
    float* __restrict__ out)                // (B,64,HW) f32
{
    __shared__ unsigned int patch[PR * PC * PST];   // 34.56 KB

    int t = threadIdx.x;
    int lane = t & 63;
    int wid = t >> 6;
    int bid = blockIdx.x;
    int b = bid & 7;                        // image -> XCD
    int tile = bid >> 3;                    // 0..127
    int ho0 = (tile >> 3) * TR;
    int wo0 = (tile & 7) * TC;
    int py0 = ho0 - HALO;
    int px0 = wo0 - HALO;

    int q = lane & 31;                      // pixel within wave
    int hi = lane >> 5;                     // channel-half
    int ho = ho0 + 2 * wid + (q >> 4);
    int wo = wo0 + (q & 15);
    int p = ho * WW + wo;

    const unsigned int* xb = xT + (size_t)b * HW * 32;
    const short8* wAv = (const short8*)wA;
    const short8* owAv = (const short8*)owA;

    // ---------------- stage patch (coalesced, clamped) ----------------
#pragma unroll
    for (int it = 0; it < 8; ++it) {
        int id = it * 256 + t;
        if (id < PR * PC * 8) {             // 1920 16B-chunks
            int row = id / (PC * 8);
            int rem = id - row * (PC * 8);
            int col = rem >> 3;
            int c = rem & 7;
            int yc = min(max(py0 + row, 0), HH - 1);
            int xc = min(max(px0 + col, 0), WW - 1);
            u32x4 v = *(const u32x4*)(xb + (size_t)(yc * WW + xc) * 32 + c * 4);
            *(u32x4*)&patch[(row * PC + col) * PST + c * 4] = v;
        }
    }
    __syncthreads();                        // the ONLY barrier

    // ---------------- phase 1: offset conv ----------------
    f32x16 acc1 = {};
#pragma unroll
    for (int kk = 0; kk < 9; ++kk) {
        int iy = ho + kk / 3 - 1;
        int ix = wo + kk % 3 - 1;
        bool ok = ((unsigned)iy < 128u) && ((unsigned)ix < 128u);
        int jy = min(max(iy, 0), 127) - py0;
        int jx = min(max(ix, 0), 127) - px0;
        int base = (jy * PC + jx) * PST + (hi << 2);
#pragma unroll
        for (int s = 0; s < 4; ++s) {
            u32x4 raw = *(const u32x4*)&patch[base + s * 8];
            FragU bf;
#pragma unroll
            for (int j = 0; j < 4; ++j) bf.u[j] = ok ? raw[j] : 0u;
            acc1 = __builtin_amdgcn_mfma_f32_32x32x16_bf16(
                owAv[(kk * 4 + s) * 64 + lane], bf.v, acc1, 0, 0, 0);
        }
    }
    // bias + sigmoid in place; values stay in registers for __shfl
#pragma unroll
    for (int r = 0; r < 16; ++r) {
        int cout = (r & 3) + 8 * (r >> 2) + 4 * hi;
        if (cout < 27) {
            float a = acc1[r] + offset_b[cout];
            if (cout >= 18) a = 1.0f / (1.0f + __expf(-a));
            acc1[r] = a;
        }
    }

    // ---------------- phase 2: deformable conv ----------------
    f32x16 acc[2];
#pragma unroll
    for (int m = 0; m < 2; ++m) {
#pragma unroll
        for (int r = 0; r < 16; ++r) {
            acc[m][r] = bias[m * 32 + (r & 3) + 8 * (r >> 2) + 4 * hi];
        }
    }

#pragma unroll
    for (int kk = 0; kk < 9; ++kk) {
        // fetch dy,dx,mask for this lane's pixel via cross-lane reg read
        float dy = __shfl(acc1[RR(2 * kk)],     q + HB(2 * kk));
        float dx = __shfl(acc1[RR(2 * kk + 1)], q + HB(2 * kk + 1));
        float mm = __shfl(acc1[RR(18 + kk)],    q + HB(18 + kk));

        float py = dy + (float)(kk / 3 + ho - 1);
        float px = dx + (float)(kk % 3 + wo - 1);
        float y0f = floorf(py), x0f = floorf(px);
        float wy = py - y0f, wx = px - x0f;
        int y0 = (int)y0f, x0 = (int)x0f;
        int y1 = y0 + 1, x1 = x0 + 1;
        bool y0ok = (unsigned)y0 < 128u, y1ok = (unsigned)y1 < 128u;
        bool x0ok = (unsigned)x0 < 128u, x1ok = (unsigned)x1 < 128u;
        float w0 = (y0ok && x0ok) ? (1.0f - wy) * (1.0f - wx) * mm : 0.0f;
        float w1 = (y0ok && x1ok) ? (1.0f - wy) * wx * mm : 0.0f;
        float w2 = (y1ok && x0ok) ? wy * (1.0f - wx) * mm : 0.0f;
        float w3 = (y1ok && x1ok) ? wy * wx * mm : 0.0f;
        int y0c = min(max(y0, 0), 127), y1c = min(max(y1, 0), 127);
        int x0c = min(max(x0, 0), 127), x1c = min(max(x1, 0), 127);

        int jy0 = y0c - py0, jy1 = y1c - py0;
        int jx0 = x0c - px0, jx1 = x1c - px0;
        bool inp = ((unsigned)jy0 < (unsigned)PR) && ((unsigned)jy1 < (unsigned)PR) &&
                   ((unsigned)jx0 < (unsigned)PC) && ((unsigned)jx1 < (unsigned)PC);

        // A-fragments for this kk (dense 512B loads, L2-warm)
        short8 a0_0 = wAv[(kk * 4 + 0) * 64 + lane];
        short8 a0_1 = wAv[(kk * 4 + 1) * 64 + lane];
        short8 a0_2 = wAv[(kk * 4 + 2) * 64 + lane];
        short8 a0_3 = wAv[(kk * 4 + 3) * 64 + lane];
        short8 a1_0 = wAv[(36 + kk * 4 + 0) * 64 + lane];
        short8 a1_1 = wAv[(36 + kk * 4 + 1) * 64 + lane];
        short8 a1_2 = wAv[(36 + kk * 4 + 2) * 64 + lane];
        short8 a1_3 = wAv[(36 + kk * 4 + 3) * 64 + lane];

#define P2_STEP(S, A0, A1, R00, R01, R10, R11) {                            \
            short8 bf = bilerp_frag(R00, R01, R10, R11, w0, w1, w2, w3);    \
            acc[0] = __builtin_amdgcn_mfma_f32_32x32x16_bf16(A0, bf, acc[0], 0, 0, 0); \
            acc[1] = __builtin_amdgcn_mfma_f32_32x32x16_bf16(A1, bf, acc[1], 0, 0, 0); \
        }

        if (__all(inp)) {
            // fast path: corners from LDS patch
            int b00 = (jy0 * PC + jx0) * PST + (hi << 2);
            int b01 = (jy0 * PC + jx1) * PST + (hi << 2);
            int b10 = (jy1 * PC + jx0) * PST + (hi << 2);
            int b11 = (jy1 * PC + jx1) * PST + (hi << 2);
#define LRD(B, S) (*(const u32x4*)&patch[(B) + (S) * 8])
            P2_STEP(0, a0_0, a1_0, LRD(b00,0), LRD(b01,0), LRD(b10,0), LRD(b11,0));
            P2_STEP(1, a0_1, a1_1, LRD(b00,1), LRD(b01,1), LRD(b10,1), LRD(b11,1));
            P2_STEP(2, a0_2, a1_2, LRD(b00,2), LRD(b01,2), LRD(b10,2), LRD(b11,2));
            P2_STEP(3, a0_3, a1_3, LRD(b00,3), LRD(b01,3), LRD(b10,3), LRD(b11,3));
#undef LRD
        } else {
            // exact fallback: corners from global xT (rare)
            int o00 = (y0c * WW + x0c) * 32 + (hi << 2);
            int o01 = (y0c * WW + x1c) * 32 + (hi << 2);
            int o10 = (y1c * WW + x0c) * 32 + (hi << 2);
            int o11 = (y1c * WW + x1c) * 32 + (hi << 2);
#define GRD(O, S) (*(const u32x4*)(xb + (O) + (S) * 8))
            P2_STEP(0, a0_0, a1_0, GRD(o00,0), GRD(o01,0), GRD(o10,0), GRD(o11,0));
            P2_STEP(1, a0_1, a1_1, GRD(o00,1), GRD(o01,1), GRD(o10,1), GRD(o11,1));
            P2_STEP(2, a0_2, a1_2, GRD(o00,2), GRD(o01,2), GRD(o10,2), GRD(o11,2));
            P2_STEP(3, a0_3, a1_3, GRD(o00,3), GRD(o01,3), GRD(o10,3), GRD(o11,3));
#undef GRD
        }
#undef P2_STEP
    }

    // D: row(cout) = m*32 + (r&3)+8*(r>>2)+4*hi, col(pixel) = q
#pragma unroll
    for (int m = 0; m < 2; ++m) {
#pragma unroll
        for (int r = 0; r < 16; ++r) {
            int cout = m * 32 + (r & 3) + 8 * (r >> 2) + 4 * hi;
            out[((size_t)b * 64 + cout) * HW + p] = acc[m][r];
        }
    }
}

// ---------------------------------------------------------------------------
extern "C" void kernel_launch(void* const* d_in, const int* in_sizes, int n_in,
                              void* d_out, int out_size, void* d_ws, size_t ws_size,
                              hipStream_t stream) {
    const float* x        = (const float*)d_in[0];
    const float* weight   = (const float*)d_in[1];
    const float* bias     = (const float*)d_in[2];
    const float* offset_w = (const float*)d_in[3];
    const float* offset_b = (const float*)d_in[4];
    float* out = (float*)d_out;

    unsigned int* xT = (unsigned int*)d_ws;                                // B*HW*32 u32 = 16MB
    unsigned short* wA  = (unsigned short*)(xT + (size_t)BATCH * HW * 32); // 4608*8
    unsigned short* owA = wA + 4608 * 8;                                   // 2304*8

    prep_kernel<<<27, 256, 0, stream>>>(weight, offset_w, wA, owA);

    int n_tiles = BATCH * HW / 64;   // 2048
    transform_kernel<<<n_tiles, 256, 0, stream>>>(x, xT);

    int n_blocks = BATCH * HW / 128; // 1024 blocks = 8 images x 128 tiles (8x16 px)
    fused_kernel<<<n_blocks, 256, 0, stream>>>(xT, wA, owA, bias, offset_b, out);
}

// Round 10
// 57.337 us; speedup vs baseline: 2.1577x; 1.9285x over previous
//
#include <hip/hip_runtime.h>
#include <hip/hip_bf16.h>
#include <math.h>

#define HH 128
#define WW 128
#define HW 16384
#define BATCH 8

// 2D tile geometry (fused kernel)
#define TR 8            // tile rows per block
#define TC 16           // tile cols per block
#define HALO 2
#define PR 12           // TR + 2*HALO
#define PC 20           // TC + 2*HALO
#define PST 36          // dwords per patch pixel (32 data + 4 pad)

typedef __attribute__((ext_vector_type(8))) short short8;
typedef __attribute__((ext_vector_type(16))) float f32x16;
typedef __attribute__((ext_vector_type(4))) unsigned int u32x4;

union FragU { short8 v; unsigned int u[4]; u32x4 q; };

static __device__ __forceinline__ unsigned short f2bf(float f) {
    __hip_bfloat16 h = __float2bfloat16(f);
    return *(unsigned short*)&h;
}
static __device__ __forceinline__ float bf_lo(unsigned int r) {
    return __uint_as_float(r << 16);
}
static __device__ __forceinline__ float bf_hi(unsigned int r) {
    return __uint_as_float(r & 0xffff0000u);
}
static __device__ __forceinline__ short8 bilerp_frag(
    u32x4 r00, u32x4 r01, u32x4 r10, u32x4 r11,
    float w0, float w1, float w2, float w3)
{
    FragU bf;
#pragma unroll
    for (int d = 0; d < 4; ++d) {
        float se = fmaf(bf_lo(r11[d]), w3, fmaf(bf_lo(r10[d]), w2,
                   fmaf(bf_lo(r01[d]), w1, bf_lo(r00[d]) * w0)));
        float so = fmaf(bf_hi(r11[d]), w3, fmaf(bf_hi(r10[d]), w2,
                   fmaf(bf_hi(r01[d]), w1, bf_hi(r00[d]) * w0)));
        float2 f2; f2.x = se; f2.y = so;
        __hip_bfloat162 h2 = __float22bfloat162_rn(f2);
        bf.u[d] = *(unsigned int*)&h2;
    }
    return bf.v;
}

// ---------------------------------------------------------------------------
// Prep: pack weights for 32x32x16 MFMA A-operand, bf16 (verified r8).
// A lane l: row = l&31, k-elems j=0..7 -> channel c = s*16 + 8*(l>>5) + j
//   wA : (m=2, kk=9, s=4, lane=64, j=8) bf16   <- weight (64,64,3,3)
//   owA: (kk=9, s=4, lane=64, j=8)      bf16   <- offset_w (27,64,3,3)
// ---------------------------------------------------------------------------
__global__ __launch_bounds__(256) void prep_kernel(
    const float* __restrict__ weight,
    const float* __restrict__ offset_w,
    unsigned short* __restrict__ wA,
    unsigned short* __restrict__ owA)
{
    int id = blockIdx.x * 256 + threadIdx.x;
    if (id < 4608) {                        // 2*9*4*64
        int m = id / 2304;
        int rem = id % 2304;
        int kk = rem >> 8;
        int s = (rem >> 6) & 3;
        int l = id & 63;
        int cout = m * 32 + (l & 31);
        int cbase = s * 16 + 8 * (l >> 5);
#pragma unroll
        for (int j = 0; j < 8; ++j) {
            wA[id * 8 + j] = f2bf(weight[(cout * 64 + cbase + j) * 9 + kk]);
        }
        return;
    }
    int id2 = id - 4608;
    if (id2 < 2304) {                       // 9*4*64
        int kk = id2 >> 8;
        int s = (id2 >> 6) & 3;
        int l = id2 & 63;
        int cout = l & 31;
        int cbase = s * 16 + 8 * (l >> 5);
#pragma unroll
        for (int j = 0; j < 8; ++j) {
            float v = (cout < 27) ? offset_w[(cout * 64 + cbase + j) * 9 + kk] : 0.0f;
            owA[id2 * 8 + j] = f2bf(v);
        }
    }
}

// ---------------------------------------------------------------------------
// Transform: x NCHW fp32 -> xT NHWC bf16 (u32 channel-pairs), LDS-tiled.
// ---------------------------------------------------------------------------
__global__ __launch_bounds__(256) void transform_kernel(
    const float* __restrict__ x,
    unsigned int* __restrict__ xT)
{
    __shared__ unsigned int lds[64][33];
    int bid = blockIdx.x;
    int b = bid & 7;                        // image -> XCD
    int pix0 = (bid >> 3) << 6;
    int t = threadIdx.x;
    int px = t & 63;
    int cp0 = (t >> 6) * 8;

    const float* xb = x + (size_t)b * 64 * HW + pix0 + px;
#pragma unroll
    for (int it = 0; it < 8; ++it) {
        int cpair = cp0 + it;
        float2 f2;
        f2.x = xb[(size_t)(2 * cpair) * HW];
        f2.y = xb[(size_t)(2 * cpair + 1) * HW];
        __hip_bfloat162 h2 = __float22bfloat162_rn(f2);
        lds[px][cpair] = *(unsigned int*)&h2;
    }
    __syncthreads();

    int wpx = t >> 2, qq = t & 3;
    unsigned int* dst = xT + ((size_t)b * HW + pix0 + wpx) * 32 + qq * 8;
    u32x4 a, c;
#pragma unroll
    for (int j = 0; j < 4; ++j) a[j] = lds[wpx][qq * 8 + j];
#pragma unroll
    for (int j = 0; j < 4; ++j) c[j] = lds[wpx][qq * 8 + 4 + j];
    *(u32x4*)dst = a;
    *(u32x4*)(dst + 4) = c;
}

// ---------------------------------------------------------------------------
// Fused kernel, LDS-patch v2 (register-pressure-fixed).
//   Changes vs r9 (which spilled ~100B/lane to scratch: FETCH 98MB):
//     - phase-1 results go straight to per-wave LDS red[wid][27][33];
//       acc1 is dead before phase 2 (no __shfl, no 16 extra live VGPRs).
//     - A-fragments loaded just-in-time inside each s-step (2 live, not 8).
//     - __launch_bounds__(256,3): ~168-reg budget; LDS 48.8KB -> 3 blocks/CU.
// ---------------------------------------------------------------------------
__global__ __launch_bounds__(256, 3) void fused_kernel(
    const unsigned int* __restrict__ xT,    // NHWC bf16
    const unsigned short* __restrict__ wA,  // (2,9,4,64,8) bf16
    const unsigned short* __restrict__ owA, // (9,4,64,8) bf16
    const float* __restrict__ bias,         // (64,)
    const float* __restrict__ offset_b,     // (27,)
    float* __restrict__ out)                // (B,64,HW) f32
{
    __shared__ unsigned int patch[PR * PC * PST];   // 34.56 KB
    __shared__ float red[4][27][33];                // 14.26 KB per-wave off/mask

    int t = threadIdx.x;
    int lane = t & 63;
    int wid = t >> 6;
    int bid = blockIdx.x;
    int b = bid & 7;                        // image -> XCD
    int tile = bid >> 3;                    // 0..127
    int ho0 = (tile >> 3) * TR;
    int wo0 = (tile & 7) * TC;
    int py0 = ho0 - HALO;
    int px0 = wo0 - HALO;

    int q = lane & 31;                      // pixel within wave
    int hi = lane >> 5;                     // channel-half
    int ho = ho0 + 2 * wid + (q >> 4);
    int wo = wo0 + (q & 15);
    int p = ho * WW + wo;

    const unsigned int* xb = xT + (size_t)b * HW * 32;
    const short8* wAv = (const short8*)wA;
    const short8* owAv = (const short8*)owA;

    // ---------------- stage patch (coalesced, clamped) ----------------
#pragma unroll
    for (int it = 0; it < 8; ++it) {
        int id = it * 256 + t;
        if (id < PR * PC * 8) {             // 1920 16B-chunks
            int row = id / (PC * 8);
            int rem = id - row * (PC * 8);
            int col = rem >> 3;
            int c = rem & 7;
            int yc = min(max(py0 + row, 0), HH - 1);
            int xc = min(max(px0 + col, 0), WW - 1);
            u32x4 v = *(const u32x4*)(xb + (size_t)(yc * WW + xc) * 32 + c * 4);
            *(u32x4*)&patch[(row * PC + col) * PST + c * 4] = v;
        }
    }
    __syncthreads();                        // the ONLY barrier

    // ---------------- phase 1: offset conv ----------------
    {
        f32x16 acc1 = {};
#pragma unroll
        for (int kk = 0; kk < 9; ++kk) {
            int iy = ho + kk / 3 - 1;
            int ix = wo + kk % 3 - 1;
            bool ok = ((unsigned)iy < 128u) && ((unsigned)ix < 128u);
            int jy = min(max(iy, 0), 127) - py0;
            int jx = min(max(ix, 0), 127) - px0;
            int base = (jy * PC + jx) * PST + (hi << 2);
#pragma unroll
            for (int s = 0; s < 4; ++s) {
                u32x4 raw = *(const u32x4*)&patch[base + s * 8];
                FragU bf;
#pragma unroll
                for (int j = 0; j < 4; ++j) bf.u[j] = ok ? raw[j] : 0u;
                acc1 = __builtin_amdgcn_mfma_f32_32x32x16_bf16(
                    owAv[(kk * 4 + s) * 64 + lane], bf.v, acc1, 0, 0, 0);
            }
        }
        // bias + sigmoid; write to per-wave LDS slice (no barrier needed);
        // acc1 dies here -> phase 2 starts with a clean register file.
#pragma unroll
        for (int r = 0; r < 16; ++r) {
            int cout = (r & 3) + 8 * (r >> 2) + 4 * hi;
            if (cout < 27) {
                float a = acc1[r] + offset_b[cout];
                if (cout >= 18) a = 1.0f / (1.0f + __expf(-a));
                red[wid][cout][q] = a;
            }
        }
    }

    // ---------------- phase 2: deformable conv ----------------
    f32x16 acc[2];
#pragma unroll
    for (int m = 0; m < 2; ++m) {
#pragma unroll
        for (int r = 0; r < 16; ++r) {
            acc[m][r] = bias[m * 32 + (r & 3) + 8 * (r >> 2) + 4 * hi];
        }
    }

    for (int kk = 0; kk < 9; ++kk) {
        float dy = red[wid][2 * kk][q];
        float dx = red[wid][2 * kk + 1][q];
        float mm = red[wid][18 + kk][q];

        float py = dy + (float)(kk / 3 + ho - 1);
        float px = dx + (float)(kk % 3 + wo - 1);
        float y0f = floorf(py), x0f = floorf(px);
        float wy = py - y0f, wx = px - x0f;
        int y0 = (int)y0f, x0 = (int)x0f;
        int y1 = y0 + 1, x1 = x0 + 1;
        bool y0ok = (unsigned)y0 < 128u, y1ok = (unsigned)y1 < 128u;
        bool x0ok = (unsigned)x0 < 128u, x1ok = (unsigned)x1 < 128u;
        float w0 = (y0ok && x0ok) ? (1.0f - wy) * (1.0f - wx) * mm : 0.0f;
        float w1 = (y0ok && x1ok) ? (1.0f - wy) * wx * mm : 0.0f;
        float w2 = (y1ok && x0ok) ? wy * (1.0f - wx) * mm : 0.0f;
        float w3 = (y1ok && x1ok) ? wy * wx * mm : 0.0f;
        int y0c = min(max(y0, 0), 127), y1c = min(max(y1, 0), 127);
        int x0c = min(max(x0, 0), 127), x1c = min(max(x1, 0), 127);

        int jy0 = y0c - py0, jy1 = y1c - py0;
        int jx0 = x0c - px0, jx1 = x1c - px0;
        bool inp = ((unsigned)jy0 < (unsigned)PR) && ((unsigned)jy1 < (unsigned)PR) &&
                   ((unsigned)jx0 < (unsigned)PC) && ((unsigned)jx1 < (unsigned)PC);

        // A-frags loaded just-in-time inside each step: only 2 live at once.
#define P2_STEP(S, R00, R01, R10, R11) {                                    \
            short8 A0 = wAv[(kk * 4 + (S)) * 64 + lane];                    \
            short8 A1 = wAv[(36 + kk * 4 + (S)) * 64 + lane];               \
            short8 bf = bilerp_frag(R00, R01, R10, R11, w0, w1, w2, w3);    \
            acc[0] = __builtin_amdgcn_mfma_f32_32x32x16_bf16(A0, bf, acc[0], 0, 0, 0); \
            acc[1] = __builtin_amdgcn_mfma_f32_32x32x16_bf16(A1, bf, acc[1], 0, 0, 0); \
        }

        if (__all(inp)) {
            int b00 = (jy0 * PC + jx0) * PST + (hi << 2);
            int b01 = (jy0 * PC + jx1) * PST + (hi << 2);
            int b10 = (jy1 * PC + jx0) * PST + (hi << 2);
            int b11 = (jy1 * PC + jx1) * PST + (hi << 2);
#define LRD(B, S) (*(const u32x4*)&patch[(B) + (S) * 8])
            P2_STEP(0, LRD(b00,0), LRD(b01,0), LRD(b10,0), LRD(b11,0));
            P2_STEP(1, LRD(b00,1), LRD(b01,1), LRD(b10,1), LRD(b11,1));
            P2_STEP(2, LRD(b00,2), LRD(b01,2), LRD(b10,2), LRD(b11,2));
            P2_STEP(3, LRD(b00,3), LRD(b01,3), LRD(b10,3), LRD(b11,3));
#undef LRD
        } else {
            int o00 = (y0c * WW + x0c) * 32 + (hi << 2);
            int o01 = (y0c * WW + x1c) * 32 + (hi << 2);
            int o10 = (y1c * WW + x0c) * 32 + (hi << 2);
            int o11 = (y1c * WW + x1c) * 32 + (hi << 2);
#define GRD(O, S) (*(const u32x4*)(xb + (O) + (S) * 8))
            P2_STEP(0, GRD(o00,0), GRD(o01,0), GRD(o10,0), GRD(o11,0));
            P2_STEP(1, GRD(o00,1), GRD(o01,1), GRD(o10,1), GRD(o11,1));
            P2_STEP(2, GRD(o00,2), GRD(o01,2), GRD(o10,2), GRD(o11,2));
            P2_STEP(3, GRD(o00,3), GRD(o01,3), GRD(o10,3), GRD(o11,3));
#undef GRD
        }
#undef P2_STEP
    }

    // D: row(cout) = m*32 + (r&3)+8*(r>>2)+4*hi, col(pixel) = q
#pragma unroll
    for (int m = 0; m < 2; ++m) {
#pragma unroll
        for (int r = 0; r < 16; ++r) {
            int cout = m * 32 + (r & 3) + 8 * (r >> 2) + 4 * hi;
            out[((size_t)b * 64 + cout) * HW + p] = acc[m][r];
        }
    }
}

// ---------------------------------------------------------------------------
extern "C" void kernel_launch(void* const* d_in, const int* in_sizes, int n_in,
                              void* d_out, int out_size, void* d_ws, size_t ws_size,
                              hipStream_t stream) {
    const float* x        = (const float*)d_in[0];
    const float* weight   = (const float*)d_in[1];
    const float* bias     = (const float*)d_in[2];
    const float* offset_w = (const float*)d_in[3];
    const float* offset_b = (const float*)d_in[4];
    float* out = (float*)d_out;

    unsigned int* xT = (unsigned int*)d_ws;                                // B*HW*32 u32 = 16MB
    unsigned short* wA  = (unsigned short*)(xT + (size_t)BATCH * HW * 32); // 4608*8
    unsigned short* owA = wA + 4608 * 8;                                   // 2304*8

    prep_kernel<<<27, 256, 0, stream>>>(weight, offset_w, wA, owA);

    int n_tiles = BATCH * HW / 64;   // 2048
    transform_kernel<<<n_tiles, 256, 0, stream>>>(x, xT);

    int n_blocks = BATCH * HW / 128; // 1024 blocks = 8 images x 128 tiles (8x16 px)
    fused_kernel<<<n_blocks, 256, 0, stream>>>(xT, wA, owA, bias, offset_b, out);
}